// Round 6
// baseline (1336.193 us; speedup 1.0000x reference)
//
#include <hip/hip_runtime.h>

// Seq2SeqRNN v6: block-local GRU (v5) + software pipelining.
// 32 blocks x 512 threads, 16 batch rows/block, full weights per block:
//   - k-chunks 0..5  -> VGPR/AGPR frags (wfr, v5-proven loader)
//   - k-chunks 6..7  -> LDS (WL)
//   - k-chunks 8..10 -> streamed from L2 (bf16 image in d_ws)
//   - W_dec          -> registers on waves 4..7 (v4-proven loader)
// New vs v5: XH operand double-buffered (parity) -> 1 barrier/encoder step,
// 2/decoder step; x_{s+1} prefetched into registers during step s (hides HBM).

#define BATCH 512
#define TSEQ  192
#define LIN_  96
#define LOUT_ 96
#define NUM_  64
#define EMB_  32
#define HID_  256
#define INS_  96

#define NBLK  32
#define NT    512          // 8 waves
#define XSTR  360          // bf16 stride, XH rows [x(96)|h(256)] (720 B, 16B-aligned)
#define WLSTR 72           // bf16 stride, WL rows (144 B; 4(row+quad)+j banks -> uniform)

// ws: bf16 image of W gate cols k=192..351 (chunks 6..10). [768][160]
#define WS_NEED 245760u

typedef __attribute__((ext_vector_type(8))) short short8_t;
typedef __attribute__((ext_vector_type(4))) float float4_t;
typedef unsigned short us;

__device__ __forceinline__ us f2bf(float x) {
    unsigned u = __builtin_bit_cast(unsigned, x);
    u = (u + 0x7FFFu + ((u >> 16) & 1u)) >> 16;
    return (us)u;
}
__device__ __forceinline__ float sigm(float x)  { return 1.0f / (1.0f + __expf(-x)); }
__device__ __forceinline__ float tanhx(float x) { return 2.0f / (1.0f + __expf(-2.0f * x)) - 1.0f; }

__device__ __forceinline__ short8_t pack8(const float* v) {
    short8_t s;
    #pragma unroll
    for (int j = 0; j < 8; ++j) s[j] = (short)f2bf(v[j]);
    return s;
}

#define MFMA16(a, b, c) __builtin_amdgcn_mfma_f32_16x16x32_bf16((a), (b), (c), 0, 0, 0)

// ============ prep: bf16 image of gate-W cols k=192..351 ============
__global__ void prep_v6(const float* __restrict__ W_hh, unsigned char* __restrict__ ws) {
    us* W2 = (us*)ws;                   // [768][160]: col c <-> k=192+c <-> W_hh col 96+c
    const int i = blockIdx.x * 256 + threadIdx.x;
    if (i < 768 * 160) {
        const int row = i / 160, c = i - row * 160;
        W2[i] = f2bf(W_hh[row * HID_ + INS_ + c]);
    }
}

// ============ main: one self-sufficient block per 16 batch rows ============
__global__ __launch_bounds__(NT, 2) void gru_v6(
    const float* __restrict__ input_num, const int* __restrict__ input_cat,
    const float* __restrict__ emb_table,
    const float* __restrict__ W_ih, const float* __restrict__ W_hh,
    const float* __restrict__ b_ih, const float* __restrict__ b_hh,
    const float* __restrict__ W_dec, const float* __restrict__ b_dec,
    const unsigned char* __restrict__ ws, float* __restrict__ out)
{
    __shared__ __align__(16) us XH[2][16 * XSTR];    // parity-double-buffered operand
    __shared__ __align__(16) us WL[768 * WLSTR];     // gate-W k-chunks 6,7 (k=192..255)

    const us* W2 = (const us*)ws;

    const int t = threadIdx.x, wave = t >> 6, lane = t & 63;
    const int arow = lane & 15, quad = lane >> 4, kq = quad * 8;
    const int bb = blockIdx.x * 16;

    // ---- one-time: VGPR gate-weight frags, k-chunks 0..5 (v5-proven) ----
    short8_t wfr[2][3][6];
    #pragma unroll
    for (int ti = 0; ti < 2; ++ti) {
        #pragma unroll
        for (int g3 = 0; g3 < 3; ++g3) {
            const int grow = g3 * HID_ + 32 * wave + 16 * ti + arow;
            #pragma unroll
            for (int kc = 0; kc < 6; ++kc) {
                float tmp[8];
                #pragma unroll
                for (int j2 = 0; j2 < 2; ++j2) {
                    const int k = kc * 32 + kq + j2 * 4;
                    float4 v = (k < INS_)
                        ? *(const float4*)&W_ih[(size_t)grow * INS_ + k]
                        : *(const float4*)&W_hh[(size_t)grow * HID_ + (k - INS_)];
                    tmp[j2 * 4 + 0] = v.x; tmp[j2 * 4 + 1] = v.y;
                    tmp[j2 * 4 + 2] = v.z; tmp[j2 * 4 + 3] = v.w;
                }
                wfr[ti][g3][kc] = pack8(tmp);
            }
        }
    }
    // ---- one-time: W_dec frags in regs (v4-proven loader; used by waves 4..7) ----
    short8_t wd[8];
    {
        const int nrow = (wave & 3) * 16 + arow;
        #pragma unroll
        for (int kc = 0; kc < 8; ++kc) {
            float tmp[8];
            #pragma unroll
            for (int j2 = 0; j2 < 2; ++j2) {
                float4 v = *(const float4*)&W_dec[(size_t)nrow * HID_ + kc * 32 + kq + j2 * 4];
                tmp[j2 * 4 + 0] = v.x; tmp[j2 * 4 + 1] = v.y;
                tmp[j2 * 4 + 2] = v.z; tmp[j2 * 4 + 3] = v.w;
            }
            wd[kc] = pack8(tmp);
        }
    }

    // ---- one-time: LDS staging of WL (chunks 6,7 from W2 cols 0..63) ----
    for (int c = t; c < 768 * 8; c += NT) {
        const int row = c >> 3, q = c & 7;
        *(ulonglong2*)&WL[row * WLSTR + q * 8] = *(const ulonglong2*)&W2[row * 160 + q * 8];
    }

    // ---- one-time: per-lane biases ----
    float bRr[2], bZr[2], bNXr[2], bNHr[2];
    #pragma unroll
    for (int ti = 0; ti < 2; ++ti) {
        const int u = 32 * wave + 16 * ti + arow;
        bRr[ti]  = b_ih[u] + b_hh[u];
        bZr[ti]  = b_ih[HID_ + u] + b_hh[HID_ + u];
        bNXr[ti] = b_ih[2 * HID_ + u];
        bNHr[ti] = b_hh[2 * HID_ + u];
    }
    const float bdr = b_dec[(wave & 3) * 16 + arow];
    float hr[2][4] = {{0.f,0.f,0.f,0.f},{0.f,0.f,0.f,0.f}};

    // ---- register prefetch of x_1 ----
    float4 pf_num = {0.f,0.f,0.f,0.f}, pf_emb = {0.f,0.f,0.f,0.f};
    {
        if (t < 256) {
            const int row = t >> 4, q = t & 15;
            pf_num = *(const float4*)&input_num[((size_t)(bb + row) * TSEQ + 0) * NUM_ + q * 4];
        } else if (t < 384) {
            const int e = t - 256, row = e >> 3, q = e & 7;
            const int cat = input_cat[(bb + row) * TSEQ + 0];
            pf_emb = *(const float4*)&emb_table[cat * EMB_ + q * 4];
        }
    }

    // ======== 191 sequential GRU steps ========
    for (int sg = 1; sg <= 191; ++sg) {
        us* X = XH[sg & 1];

        // (W) write phase: h_{sg-1} from hr regs; x_sg from prefetch regs
        #pragma unroll
        for (int ti = 0; ti < 2; ++ti) {
            #pragma unroll
            for (int i = 0; i < 4; ++i)
                X[(quad * 4 + i) * XSTR + INS_ + 32 * wave + 16 * ti + arow] = f2bf(hr[ti][i]);
        }
        if (sg <= 96) {
            if (t < 256) {
                const int row = t >> 4, q = t & 15;
                ushort4 s = { f2bf(pf_num.x), f2bf(pf_num.y), f2bf(pf_num.z), f2bf(pf_num.w) };
                *(ushort4*)&X[row * XSTR + q * 4] = s;
            } else if (t < 384) {
                const int e = t - 256, row = e >> 3, q = e & 7;
                ushort4 s = { f2bf(pf_emb.x), f2bf(pf_emb.y), f2bf(pf_emb.z), f2bf(pf_emb.w) };
                *(ushort4*)&X[row * XSTR + NUM_ + q * 4] = s;
            }
        } else {
            if (t < 128) {
                const int row = t >> 3, q = t & 7;
                ushort4 s = { f2bf(pf_emb.x), f2bf(pf_emb.y), f2bf(pf_emb.z), f2bf(pf_emb.w) };
                *(ushort4*)&X[row * XSTR + NUM_ + q * 4] = s;
            }
        }
        __syncthreads();   // B1: h + staged x visible

        // (P) prefetch x_{sg+1} into regs (consumed next step; latency hidden)
        if (sg < 96) {
            if (t < 256) {
                const int row = t >> 4, q = t & 15;
                pf_num = *(const float4*)&input_num[((size_t)(bb + row) * TSEQ + sg) * NUM_ + q * 4];
            } else if (t < 384) {
                const int e = t - 256, row = e >> 3, q = e & 7;
                const int cat = input_cat[(bb + row) * TSEQ + sg];
                pf_emb = *(const float4*)&emb_table[cat * EMB_ + q * 4];
            }
        } else if (sg < 191) {
            if (t < 128) {
                const int row = t >> 3, q = t & 7;
                const int cat = input_cat[(bb + row) * TSEQ + sg];
                pf_emb = *(const float4*)&emb_table[cat * EMB_ + q * 4];
            }
        }

        // (C) decoder (waves 4..7): out_{sg-97} = h_{sg-1} @ W_dec^T + b; feedback -> X[0..63]
        if (sg > 96) {
            if (wave >= 4) {
                float4_t a0 = {0.f,0.f,0.f,0.f}, a1 = {0.f,0.f,0.f,0.f};
                #pragma unroll
                for (int kc = 0; kc < 8; kc += 2) {
                    short8_t aA = *(const short8_t*)&X[arow * XSTR + INS_ + kc * 32 + kq];
                    short8_t aB = *(const short8_t*)&X[arow * XSTR + INS_ + (kc + 1) * 32 + kq];
                    a0 = MFMA16(aA, wd[kc], a0);
                    a1 = MFMA16(aB, wd[kc + 1], a1);
                }
                const int cg = (wave - 4) * 16 + arow, pos = sg - 97;
                #pragma unroll
                for (int i = 0; i < 4; ++i) {
                    const int row = quad * 4 + i;
                    const float val = a0[i] + a1[i] + bdr;
                    X[row * XSTR + cg] = f2bf(val);
                    out[((size_t)(bb + row) * LOUT_ + pos) * NUM_ + cg] = val;
                }
            }
            __syncthreads();   // B2: feedback visible
        }

        // (D)+(E) gates + pure-register pointwise (v5-proven math)
        #pragma unroll
        for (int ti = 0; ti < 2; ++ti) {
            short8_t sw[3][3];
            #pragma unroll
            for (int g3 = 0; g3 < 3; ++g3) {
                const int grow = g3 * HID_ + 32 * wave + 16 * ti + arow;
                #pragma unroll
                for (int sc = 0; sc < 3; ++sc)
                    sw[g3][sc] = *(const short8_t*)&W2[(size_t)grow * 160 + 64 + sc * 32 + kq];
            }
            float4_t aR = {0.f,0.f,0.f,0.f}, aZ = {0.f,0.f,0.f,0.f};
            float4_t aNX = {0.f,0.f,0.f,0.f}, aNH = {0.f,0.f,0.f,0.f};
            #pragma unroll
            for (int kc = 0; kc < 6; ++kc) {
                short8_t a = *(const short8_t*)&X[arow * XSTR + kc * 32 + kq];
                aR = MFMA16(a, wfr[ti][0][kc], aR);
                aZ = MFMA16(a, wfr[ti][1][kc], aZ);
                if (kc < 3) aNX = MFMA16(a, wfr[ti][2][kc], aNX);
                else        aNH = MFMA16(a, wfr[ti][2][kc], aNH);
            }
            #pragma unroll
            for (int kc = 6; kc < 8; ++kc) {
                short8_t a = *(const short8_t*)&X[arow * XSTR + kc * 32 + kq];
                const int wbase = 32 * wave + 16 * ti + arow;
                short8_t b0 = *(const short8_t*)&WL[(0 * HID_ + wbase) * WLSTR + (kc - 6) * 32 + kq];
                short8_t b1 = *(const short8_t*)&WL[(1 * HID_ + wbase) * WLSTR + (kc - 6) * 32 + kq];
                short8_t b2 = *(const short8_t*)&WL[(2 * HID_ + wbase) * WLSTR + (kc - 6) * 32 + kq];
                aR = MFMA16(a, b0, aR);
                aZ = MFMA16(a, b1, aZ);
                aNH = MFMA16(a, b2, aNH);
            }
            #pragma unroll
            for (int sc = 0; sc < 3; ++sc) {
                short8_t a = *(const short8_t*)&X[arow * XSTR + (8 + sc) * 32 + kq];
                aR = MFMA16(a, sw[0][sc], aR);
                aZ = MFMA16(a, sw[1][sc], aZ);
                aNH = MFMA16(a, sw[2][sc], aNH);
            }
            #pragma unroll
            for (int i = 0; i < 4; ++i) {
                const float r = sigm(aR[i] + bRr[ti]);
                const float z = sigm(aZ[i] + bZr[ti]);
                const float n = tanhx(aNX[i] + bNXr[ti] + r * (aNH[i] + bNHr[ti]));
                hr[ti][i] = (1.0f - z) * n + z * hr[ti][i];
            }
        }
        // no end barrier: step sg+1 writes the OTHER XH buffer (WAR-safe by parity)
    }

    // ======== epilogue: out position 95 from h_191 ========
    {
        us* X = XH[0];   // parity of "step 192"
        #pragma unroll
        for (int ti = 0; ti < 2; ++ti) {
            #pragma unroll
            for (int i = 0; i < 4; ++i)
                X[(quad * 4 + i) * XSTR + INS_ + 32 * wave + 16 * ti + arow] = f2bf(hr[ti][i]);
        }
        __syncthreads();
        if (wave >= 4) {
            float4_t a0 = {0.f,0.f,0.f,0.f}, a1 = {0.f,0.f,0.f,0.f};
            #pragma unroll
            for (int kc = 0; kc < 8; kc += 2) {
                short8_t aA = *(const short8_t*)&X[arow * XSTR + INS_ + kc * 32 + kq];
                short8_t aB = *(const short8_t*)&X[arow * XSTR + INS_ + (kc + 1) * 32 + kq];
                a0 = MFMA16(aA, wd[kc], a0);
                a1 = MFMA16(aB, wd[kc + 1], a1);
            }
            const int cg = (wave - 4) * 16 + arow;
            #pragma unroll
            for (int i = 0; i < 4; ++i) {
                const int row = quad * 4 + i;
                out[((size_t)(bb + row) * LOUT_ + 95) * NUM_ + cg] = a0[i] + a1[i] + bdr;
            }
        }
    }
}

// ============ fallback (v1 logic, known-passing fp32) if ws too small ============
__global__ __launch_bounds__(512) void gru_fallback(
    const float* __restrict__ input_num, const int* __restrict__ input_cat,
    const float* __restrict__ emb_table,
    const float* __restrict__ W_ih, const float* __restrict__ W_hh,
    const float* __restrict__ b_ih, const float* __restrict__ b_hh,
    const float* __restrict__ W_dec, const float* __restrict__ b_dec,
    float* __restrict__ out)
{
    __shared__ __align__(16) float xh[4][352];
    __shared__ float wdec[NUM_ * 257];
    const int t = threadIdx.x, bbase = blockIdx.x * 4;
    const int u = t & 255, rb = (t >> 8) * 2;
    for (int i = t; i < NUM_ * HID_; i += 512) wdec[(i >> 8) * 257 + (i & 255)] = W_dec[i];
    for (int i = t; i < 4 * HID_; i += 512) xh[i >> 8][INS_ + (i & 255)] = 0.0f;
    const float bR = b_ih[u] + b_hh[u], bZ = b_ih[256 + u] + b_hh[256 + u];
    const float bNX = b_ih[512 + u], bNH = b_hh[512 + u], bD = b_dec[t & 63];
    __syncthreads();
    auto step = [&]() {
        float aR0 = bR, aR1 = bR, aZ0 = bZ, aZ1 = bZ, aNX0 = bNX, aNX1 = bNX, aNH0 = bNH, aNH1 = bNH;
        const float* x0 = xh[rb]; const float* x1 = xh[rb + 1];
        for (int kb = 0; kb < 88; ++kb) {
            float4 w0, w1, w2; int k4 = kb * 4;
            if (k4 < INS_) {
                w0 = *(const float4*)&W_ih[(size_t)u * INS_ + k4];
                w1 = *(const float4*)&W_ih[(size_t)(256 + u) * INS_ + k4];
                w2 = *(const float4*)&W_ih[(size_t)(512 + u) * INS_ + k4];
            } else {
                int kh = k4 - INS_;
                w0 = *(const float4*)&W_hh[(size_t)u * HID_ + kh];
                w1 = *(const float4*)&W_hh[(size_t)(256 + u) * HID_ + kh];
                w2 = *(const float4*)&W_hh[(size_t)(512 + u) * HID_ + kh];
            }
            float4 a = *(const float4*)&x0[k4], c = *(const float4*)&x1[k4];
            aR0 += w0.x*a.x+w0.y*a.y+w0.z*a.z+w0.w*a.w; aR1 += w0.x*c.x+w0.y*c.y+w0.z*c.z+w0.w*c.w;
            aZ0 += w1.x*a.x+w1.y*a.y+w1.z*a.z+w1.w*a.w; aZ1 += w1.x*c.x+w1.y*c.y+w1.z*c.z+w1.w*c.w;
            if (k4 < INS_) { aNX0 += w2.x*a.x+w2.y*a.y+w2.z*a.z+w2.w*a.w; aNX1 += w2.x*c.x+w2.y*c.y+w2.z*c.z+w2.w*c.w; }
            else           { aNH0 += w2.x*a.x+w2.y*a.y+w2.z*a.z+w2.w*a.w; aNH1 += w2.x*c.x+w2.y*c.y+w2.z*c.z+w2.w*c.w; }
        }
        float h0 = x0[INS_ + u], h1 = x1[INS_ + u];
        __syncthreads();
        { float r = sigm(aR0), z = sigm(aZ0), n = tanhx(aNX0 + r * aNH0);
          xh[rb][INS_ + u] = (1 - z) * n + z * h0; }
        { float r = sigm(aR1), z = sigm(aZ1), n = tanhx(aNX1 + r * aNH1);
          xh[rb + 1][INS_ + u] = (1 - z) * n + z * h1; }
        __syncthreads();
    };
    auto project = [&](int pos) {
        if (t < 256) {
            int r = t >> 6, m = t & 63;
            const float* wr = &wdec[m * 257]; const float* hr2 = &xh[r][INS_];
            float acc = bD;
            for (int k = 0; k < HID_; ++k) acc = fmaf(wr[k], hr2[k], acc);
            out[((size_t)(bbase + r) * LOUT_ + pos) * NUM_ + m] = acc;
            xh[r][m] = acc;
        }
    };
    for (int s = 0; s < LIN_; ++s) {
        if (t < 256) { int r = t >> 6, k = t & 63;
            xh[r][k] = input_num[((size_t)(bbase + r) * TSEQ + s) * NUM_ + k]; }
        if (t < 128) { int r = t >> 5, e = t & 31;
            xh[r][NUM_ + e] = emb_table[input_cat[(bbase + r) * TSEQ + s] * EMB_ + e]; }
        __syncthreads();
        step();
    }
    project(0);
    for (int s = 0; s < LOUT_ - 1; ++s) {
        if (t < 128) { int r = t >> 5, e = t & 31;
            xh[r][NUM_ + e] = emb_table[input_cat[(bbase + r) * TSEQ + LIN_ + s] * EMB_ + e]; }
        __syncthreads();
        step();
        project(s + 1);
    }
}

extern "C" void kernel_launch(void* const* d_in, const int* in_sizes, int n_in,
                              void* d_out, int out_size, void* d_ws, size_t ws_size,
                              hipStream_t stream) {
    const float* input_num = (const float*)d_in[0];
    const int*   input_cat = (const int*)d_in[1];
    const float* emb_table = (const float*)d_in[2];
    const float* W_ih      = (const float*)d_in[3];
    const float* W_hh      = (const float*)d_in[4];
    const float* b_ih      = (const float*)d_in[5];
    const float* b_hh      = (const float*)d_in[6];
    const float* W_dec     = (const float*)d_in[7];
    const float* b_dec     = (const float*)d_in[8];
    float* out = (float*)d_out;

    if (ws_size >= WS_NEED) {
        unsigned char* ws = (unsigned char*)d_ws;
        prep_v6<<<(768 * 160 + 255) / 256, 256, 0, stream>>>(W_hh, ws);
        gru_v6<<<NBLK, NT, 0, stream>>>(input_num, input_cat, emb_table,
                                        W_ih, W_hh, b_ih, b_hh, W_dec, b_dec, ws, out);
    } else {
        gru_fallback<<<BATCH / 4, 512, 0, stream>>>(input_num, input_cat, emb_table,
                                                    W_ih, W_hh, b_ih, b_hh, W_dec, b_dec, out);
    }
}